// Round 21
// baseline (201.496 us; speedup 1.0000x reference)
//
#include <hip/hip_runtime.h>
#include <hip/hip_bf16.h>
#include <stdint.h>

// Problem constants
#define SEQ  2048
#define DIMM 1024
#define NH   16
#define DH   64
#define NB   4
#define MROWS (NB*SEQ)   // 8192
#define QKP  2080        // padded row stride for qk/vt (breaks 4KB aliasing)

typedef __attribute__((ext_vector_type(8))) short bf16x8;
typedef __attribute__((ext_vector_type(4))) float f32x4;
typedef __attribute__((ext_vector_type(16))) float f32x16;

#define LOG2E 1.44269504088896340736f

template<bool B> struct BoolC { static constexpr bool value = B; };

__device__ __forceinline__ unsigned short f2bf(float f) {
    union { float f; uint32_t u; } c; c.f = f;
    uint32_t r = c.u + 0x7fff + ((c.u >> 16) & 1);
    return (unsigned short)(r >> 16);
}

__device__ __forceinline__ void gload_lds16(const void* g, void* lds) {
    __builtin_amdgcn_global_load_lds(
        (const __attribute__((address_space(1))) unsigned int*)(g),
        (__attribute__((address_space(3))) unsigned int*)(lds),
        16, 0, 0);
}

// ---- fused prep: x fp32->bf16 convert + both weight transposes ------------
__global__ __launch_bounds__(256) void k_prep(const float* __restrict__ x,
                                              unsigned short* __restrict__ x_bf,
                                              const float* __restrict__ w_qkv,
                                              unsigned short* __restrict__ wqkvT,
                                              const float* __restrict__ w_out,
                                              unsigned short* __restrict__ woutT) {
    __shared__ unsigned short tile[32][33];
    const int bid = blockIdx.x;
    if (bid < 8192) {
        int i = bid * 256 + threadIdx.x;
        float4 v = ((const float4*)x)[i];
        ushort4 o;
        o.x = f2bf(v.x); o.y = f2bf(v.y); o.z = f2bf(v.z); o.w = f2bf(v.w);
        ((ushort4*)x_bf)[i] = o;
        return;
    }
    const float* W;
    unsigned short* Wt;
    int tn, tk, N;
    if (bid < 8192 + 3072) {
        W = w_qkv; Wt = wqkvT; N = 3072;
        tn = (bid - 8192) % 96; tk = (bid - 8192) / 96;
    } else {
        W = w_out; Wt = woutT; N = 1024;
        tn = (bid - 11264) % 32; tk = (bid - 11264) / 32;
    }
    const int K = 1024;
    int lx = threadIdx.x & 31, ly = threadIdx.x >> 5;  // 32 x 8
    #pragma unroll
    for (int i = 0; i < 32; i += 8) {
        int k = tk * 32 + ly + i;
        int n = tn * 32 + lx;
        tile[ly + i][lx] = f2bf(W[(size_t)k * N + n]);
    }
    __syncthreads();
    int k2 = tk * 32 + lx;
    #pragma unroll
    for (int i = 0; i < 32; i += 8) {
        int n2 = tn * 32 + ly + i;
        Wt[(size_t)n2 * K + k2] = tile[lx][ly + i];
    }
}

// ---- 8-phase-style QKV GEMM: C[8192][3072] tiles 128x256, BK=64 ------------
// 8 waves (2M x 4N), LDS 96KB dbuf, counted vmcnt(6) (T3+T4), XOR swizzle
// (T2), setprio around MFMA clusters (T5). Fused epilogue: Q*0.125*log2e|K
// -> qk (stride QKP), V -> vt transposed. 768 blocks = 3/CU balanced.
__global__ __launch_bounds__(512, 1) void k_gemm8(const unsigned short* __restrict__ A,
                                                  const unsigned short* __restrict__ Bt,
                                                  unsigned short* __restrict__ qkv_q,
                                                  unsigned short* __restrict__ vtv) {
    __shared__ unsigned short lA[2][128 * 64];   // 2 x 16 KB
    __shared__ unsigned short lB[2][256 * 64];   // 2 x 32 KB
    const int ntile = 12;                        // 3072 / 256
    const int wgid = (blockIdx.x & 7) * 96 + (blockIdx.x >> 3);  // 768 = 8*96
    const int tm = wgid / ntile;                 // 0..63
    const int tn = wgid % ntile;                 // 0..11
    const int t = threadIdx.x;
    const int w = t >> 6, l = t & 63;
    const int wr = w >> 2, wc = w & 3;           // 2 x 4 waves

    const unsigned short* Abase = A + (size_t)tm * 128 * 1024;
    const unsigned short* Bbase = Bt + (size_t)tn * 256 * 1024;

    f32x4 acc[4][4] = {};
    const int rswz = (l & 7) << 4;

    // stage K-step ks (64 cols) into buffer bs: A 2 loads + B 4 loads / thread
    auto STAGE = [&](int ks, int bs) {
        const int k0 = ks * 64;
        #pragma unroll
        for (int i = 0; i < 2; ++i) {
            const int o  = i * 8192 + t * 16;
            const int so = o ^ (((o >> 7) & 7) << 4);
            gload_lds16((const char*)(Abase + (size_t)(so >> 7) * 1024 + k0) + (so & 127),
                        (char*)lA[bs] + i * 8192 + w * 1024);
        }
        #pragma unroll
        for (int i = 0; i < 4; ++i) {
            const int o  = i * 8192 + t * 16;
            const int so = o ^ (((o >> 7) & 7) << 4);
            gload_lds16((const char*)(Bbase + (size_t)(so >> 7) * 1024 + k0) + (so & 127),
                        (char*)lB[bs] + i * 8192 + w * 1024);
        }
    };

    // prologue: fill both buffers; wait only for buffer 0 (vmcnt 6 = STAGE(1))
    STAGE(0, 0);
    STAGE(1, 1);
    asm volatile("s_waitcnt vmcnt(6)" ::: "memory");
    __builtin_amdgcn_s_barrier();

    for (int ks = 0; ks < 16; ++ks) {
        const char* la = (const char*)lA[ks & 1];
        const char* lb = (const char*)lB[ks & 1];
        bf16x8 af[2][2], bfv[4][2];

        // group 1: A m0-1 + B all
        #pragma unroll
        for (int m = 0; m < 2; ++m)
            #pragma unroll
            for (int kk = 0; kk < 2; ++kk) {
                const int ea = ((wr * 64 + m * 16 + (l & 15)) << 7) + kk * 64 + ((l >> 4) << 4);
                af[m][kk] = *(const bf16x8*)(la + (ea ^ rswz));
            }
        #pragma unroll
        for (int n = 0; n < 4; ++n)
            #pragma unroll
            for (int kk = 0; kk < 2; ++kk) {
                const int eb = ((wc * 64 + n * 16 + (l & 15)) << 7) + kk * 64 + ((l >> 4) << 4);
                bfv[n][kk] = *(const bf16x8*)(lb + (eb ^ rswz));
            }
        __builtin_amdgcn_s_setprio(1);
        #pragma unroll
        for (int m = 0; m < 2; ++m)
            #pragma unroll
            for (int n = 0; n < 4; ++n)
                #pragma unroll
                for (int kk = 0; kk < 2; ++kk)
                    acc[m][n] = __builtin_amdgcn_mfma_f32_16x16x32_bf16(af[m][kk], bfv[n][kk], acc[m][n], 0, 0, 0);
        __builtin_amdgcn_s_setprio(0);

        // group 2 reads: A m2-3 (reuse af)
        #pragma unroll
        for (int m = 0; m < 2; ++m)
            #pragma unroll
            for (int kk = 0; kk < 2; ++kk) {
                const int ea = ((wr * 64 + (m + 2) * 16 + (l & 15)) << 7) + kk * 64 + ((l >> 4) << 4);
                af[m][kk] = *(const bf16x8*)(la + (ea ^ rswz));
            }
        __builtin_amdgcn_sched_barrier(0);     // pin reads BEFORE the barrier
        __builtin_amdgcn_s_barrier();          // all waves done reading buf[ks&1]

        // stage K-step ks+2 into the buffer we just consumed (clamped source)
        if (ks < 15) STAGE(ks + 2 < 16 ? ks + 2 : 15, ks & 1);

        __builtin_amdgcn_s_setprio(1);
        #pragma unroll
        for (int m = 0; m < 2; ++m)
            #pragma unroll
            for (int n = 0; n < 4; ++n)
                #pragma unroll
                for (int kk = 0; kk < 2; ++kk)
                    acc[m + 2][n] = __builtin_amdgcn_mfma_f32_16x16x32_bf16(af[m][kk], bfv[n][kk], acc[m + 2][n], 0, 0, 0);
        __builtin_amdgcn_s_setprio(0);

        if (ks < 15) {
            // counted wait: STAGE(ks+1) landed; STAGE(ks+2) stays in flight
            asm volatile("s_waitcnt vmcnt(6)" ::: "memory");
            __builtin_amdgcn_s_barrier();
        }
    }

    // fused epilogue
    const int row0 = tm * 128 + wr * 64 + (l >> 4) * 4;
    const int col0 = tn * 256 + wc * 64 + (l & 15);
    if (tn < 8) {
        const float cs = (tn < 4) ? 0.125f * LOG2E : 1.0f;
        #pragma unroll
        for (int i = 0; i < 4; ++i)
            #pragma unroll
            for (int j = 0; j < 4; ++j)
                #pragma unroll
                for (int r = 0; r < 4; ++r)
                    qkv_q[(size_t)(row0 + i * 16 + r) * QKP + (col0 + j * 16)] = f2bf(acc[i][j][r] * cs);
    } else {
        #pragma unroll
        for (int i = 0; i < 4; ++i) {
            const int rbase = row0 + i * 16;
            const int bq = rbase >> 11;
            const int n0 = rbase & 2047;
            #pragma unroll
            for (int j = 0; j < 4; ++j) {
                const int c = col0 + j * 16 - 2048;
                const int hh = c >> 6, dd = c & 63;
                uint2 u;
                u.x = (unsigned int)f2bf(acc[i][j][0]) | ((unsigned int)f2bf(acc[i][j][1]) << 16);
                u.y = (unsigned int)f2bf(acc[i][j][2]) | ((unsigned int)f2bf(acc[i][j][3]) << 16);
                *(uint2*)(vtv + ((size_t)(bq * 16 + hh) * 64 + dd) * QKP + n0) = u;
            }
        }
    }
}

// --------- out-proj GEMM (proven 2-phase kernel, fp32 out) ------------------
__global__ __launch_bounds__(256) void k_gemm_bt(const unsigned short* __restrict__ A,
                                                 const unsigned short* __restrict__ Bt,
                                                 float* __restrict__ Cf,
                                                 int M, int N_, int K) {
    constexpr int BM = 128, BN = 128, BK = 64;
    __shared__ unsigned short lA[BM * BK];
    __shared__ unsigned short lB[BN * BK];
    const int ntile = N_ / BN;
    const int wgid = (blockIdx.x & 7) * (gridDim.x >> 3) + (blockIdx.x >> 3);
    const int tm = wgid / ntile;
    const int tn = wgid % ntile;
    const int t = threadIdx.x;
    const int w = t >> 6, l = t & 63;
    const int wr = w >> 1, wc = w & 1;

    const unsigned short* Abase = A + (size_t)tm * BM * K;
    const unsigned short* Bbase = Bt + (size_t)tn * BN * K;

    f32x4 acc[4][4] = {};
    const int rswz = (l & 7) << 4;

    for (int k0 = 0; k0 < K; k0 += BK) {
        __syncthreads();
        #pragma unroll
        for (int i = 0; i < 4; ++i) {
            const int o  = i * 4096 + t * 16;
            const int so = o ^ (((o >> 7) & 7) << 4);
            gload_lds16((const char*)(Abase + (size_t)(so >> 7) * K + k0) + (so & 127),
                        (char*)lA + i * 4096 + w * 1024);
            gload_lds16((const char*)(Bbase + (size_t)(so >> 7) * K + k0) + (so & 127),
                        (char*)lB + i * 4096 + w * 1024);
        }
        __syncthreads();

        #pragma unroll
        for (int kk = 0; kk < 2; ++kk) {
            bf16x8 af[4], bfv[4];
            #pragma unroll
            for (int i = 0; i < 4; ++i) {
                const int ea = ((wr * 64 + i * 16 + (l & 15)) << 7) + kk * 64 + ((l >> 4) << 4);
                af[i] = *(const bf16x8*)((const char*)lA + (ea ^ rswz));
            }
            #pragma unroll
            for (int j = 0; j < 4; ++j) {
                const int eb = ((wc * 64 + j * 16 + (l & 15)) << 7) + kk * 64 + ((l >> 4) << 4);
                bfv[j] = *(const bf16x8*)((const char*)lB + (eb ^ rswz));
            }
            #pragma unroll
            for (int i = 0; i < 4; ++i)
                #pragma unroll
                for (int j = 0; j < 4; ++j)
                    acc[i][j] = __builtin_amdgcn_mfma_f32_16x16x32_bf16(af[i], bfv[j], acc[i][j], 0, 0, 0);
        }
    }

    const int row0 = tm * BM + wr * 64 + (l >> 4) * 4;
    const int col0 = tn * BN + wc * 64 + (l & 15);
    #pragma unroll
    for (int i = 0; i < 4; ++i)
        #pragma unroll
        for (int j = 0; j < 4; ++j)
            #pragma unroll
            for (int r = 0; r < 4; ++r)
                Cf[(size_t)(row0 + i * 16 + r) * N_ + (col0 + j * 16)] = acc[i][j][r];
}

// -- causal flash attention (R20 body, unchanged) ----------------------------
__global__ __launch_bounds__(256, 2) void k_attn21(const unsigned short* __restrict__ qk,
                                                   const unsigned short* __restrict__ vt,
                                                   unsigned short* __restrict__ out) {
    const int bid = blockIdx.x;               // 1024
    const int bh = bid & 63;
    const int w = threadIdx.x >> 6;
    const int c32 = 63 - ((bid >> 6) * 4 + w);
    const int b = bh >> 4, h = bh & 15;
    const int l = threadIdx.x & 63;
    const int l31 = l & 31, hi = l >> 5;

    const unsigned short* qp = qk + (size_t)(b * SEQ) * QKP + h * 64;
    unsigned short* op = out + (size_t)(b * SEQ) * DIMM + h * 64;

    constexpr int KSTEP = 64 * QKP * 2;
    constexpr int VSTEP = 64 * 2;

    union U8 { uint32_t u[4]; bf16x8 v; };

    const int q0w = c32 * 32;
    const int qrow = q0w + l31;
    const int nt = (q0w >> 6) + 1;

    bf16x8 qf[4];
    #pragma unroll
    for (int m = 0; m < 4; ++m)
        qf[m] = *(const bf16x8*)(qp + (size_t)(q0w + l31) * QKP + m * 16 + hi * 8);

    f32x16 accO0 = {}, accO1 = {};
    float m_run = -INFINITY, l_run = 0.f;

    const char* kp0 = (const char*)(qk + ((size_t)b * SEQ + l31) * QKP + 1024 + h * 64 + hi * 8);
    const char* kp1 = kp0 + 32 * QKP * 2;
    const char* vp0 = (const char*)(vt + ((size_t)bh * 64 + l31) * QKP + hi * 8);
    const char* vp1 = vp0 + 32 * QKP * 2;

    bf16x8 kf[2][4];
    #pragma unroll
    for (int m = 0; m < 4; ++m) {
        kf[0][m] = *(const bf16x8*)(kp0 + m * 32);
        kf[1][m] = *(const bf16x8*)(kp1 + m * 32);
    }
    kp0 += KSTEP; kp1 += KSTEP;

    auto tile = [&](int kv0, auto mskc) {
        constexpr bool MSK = decltype(mskc)::value;

        f32x16 s0 = {}, s1 = {};
        __builtin_amdgcn_s_setprio(1);
        #pragma unroll
        for (int m = 0; m < 4; ++m) {
            s0 = __builtin_amdgcn_mfma_f32_32x32x16_bf16(kf[0][m], qf[m], s0, 0, 0, 0);
            s1 = __builtin_amdgcn_mfma_f32_32x32x16_bf16(kf[1][m], qf[m], s1, 0, 0, 0);
        }
        __builtin_amdgcn_s_setprio(0);

        bf16x8 vf0[4], vf1[4];
        #pragma unroll
        for (int m = 0; m < 4; ++m) {
            vf0[m] = *(const bf16x8*)(vp0 + m * 32);
            vf1[m] = *(const bf16x8*)(vp1 + m * 32);
        }
        vp0 += VSTEP; vp1 += VSTEP;

        #pragma unroll
        for (int m = 0; m < 4; ++m) {
            kf[0][m] = *(const bf16x8*)(kp0 + m * 32);
            kf[1][m] = *(const bf16x8*)(kp1 + m * 32);
        }
        kp0 += KSTEP; kp1 += KSTEP;

        float tmax = -1e30f;
        #pragma unroll
        for (int r = 0; r < 16; ++r) {
            float v0 = s0[r];
            float v1 = s1[r];
            if (MSK) {
                const int crow = (r & 3) + 8 * (r >> 2) + 4 * hi;
                if (kv0 + crow > qrow)      v0 = -1e30f;
                if (kv0 + 32 + crow > qrow) v1 = -1e30f;
                s0[r] = v0; s1[r] = v1;
            }
            tmax = fmaxf(tmax, fmaxf(v0, v1));
        }
        tmax = fmaxf(tmax, __shfl_xor(tmax, 32));
        const bool defer = __all(tmax <= m_run + 8.0f);
        float fct = 1.0f;
        if (!defer) {
            const float mnew = fmaxf(m_run, tmax);
            fct = exp2f(m_run - mnew);
            m_run = mnew;
            #pragma unroll
            for (int r = 0; r < 16; ++r) { accO0[r] *= fct; accO1[r] *= fct; }
        }
        float ps = 0.f;
        #pragma unroll
        for (int r = 0; r < 16; ++r) {
            float p0 = exp2f(s0[r] - m_run);
            float p1 = exp2f(s1[r] - m_run);
            s0[r] = p0; s1[r] = p1;
            ps += p0 + p1;
        }
        ps += __shfl_xor(ps, 32);
        l_run = l_run * fct + ps;

        uint32_t pw0[8], pw1[8];
        #pragma unroll
        for (int i = 0; i < 8; ++i) {
            asm("v_cvt_pk_bf16_f32 %0, %1, %2" : "=v"(pw0[i]) : "v"(s0[2*i]), "v"(s0[2*i+1]));
            asm("v_cvt_pk_bf16_f32 %0, %1, %2" : "=v"(pw1[i]) : "v"(s1[2*i]), "v"(s1[2*i+1]));
        }
        __builtin_amdgcn_s_setprio(1);
        #define PVCHUNK(PW, BASE, VF0, VF1) do {                                     \
            uint32_t a0 = PW[BASE+0], b0 = PW[BASE+2];                               \
            uint32_t a1 = PW[BASE+1], b1 = PW[BASE+3];                               \
            asm("v_permlane32_swap_b32 %0, %1" : "+v"(a0), "+v"(b0));                \
            asm("v_permlane32_swap_b32 %0, %1" : "+v"(a1), "+v"(b1));                \
            U8 pb; pb.u[0] = a0; pb.u[1] = a1; pb.u[2] = b0; pb.u[3] = b1;           \
            accO0 = __builtin_amdgcn_mfma_f32_32x32x16_bf16(VF0, pb.v, accO0, 0, 0, 0); \
            accO1 = __builtin_amdgcn_mfma_f32_32x32x16_bf16(VF1, pb.v, accO1, 0, 0, 0); \
        } while (0)
        PVCHUNK(pw0, 0, vf0[0], vf1[0]);
        PVCHUNK(pw0, 4, vf0[1], vf1[1]);
        PVCHUNK(pw1, 0, vf0[2], vf1[2]);
        PVCHUNK(pw1, 4, vf0[3], vf1[3]);
        #undef PVCHUNK
        __builtin_amdgcn_s_setprio(0);
    };

    for (int kt = 0; kt + 1 < nt; ++kt) tile(kt * 64, BoolC<false>{});
    tile((nt - 1) * 64, BoolC<true>{});

    const float inv = 1.0f / l_run;
    unsigned short* orow = op + (size_t)(q0w + l31) * DIMM;
    #pragma unroll
    for (int g = 0; g < 4; ++g) {
        uint2 u0, u1;
        float a0 = accO0[4*g+0] * inv, a1 = accO0[4*g+1] * inv;
        float a2 = accO0[4*g+2] * inv, a3 = accO0[4*g+3] * inv;
        float c0 = accO1[4*g+0] * inv, c1 = accO1[4*g+1] * inv;
        float c2 = accO1[4*g+2] * inv, c3 = accO1[4*g+3] * inv;
        asm("v_cvt_pk_bf16_f32 %0, %1, %2" : "=v"(u0.x) : "v"(a0), "v"(a1));
        asm("v_cvt_pk_bf16_f32 %0, %1, %2" : "=v"(u0.y) : "v"(a2), "v"(a3));
        asm("v_cvt_pk_bf16_f32 %0, %1, %2" : "=v"(u1.x) : "v"(c0), "v"(c1));
        asm("v_cvt_pk_bf16_f32 %0, %1, %2" : "=v"(u1.y) : "v"(c2), "v"(c3));
        *(uint2*)(orow + 8*g + 4*hi)      = u0;
        *(uint2*)(orow + 32 + 8*g + 4*hi) = u1;
    }
}

// ---------------------------------------------------------------------------
extern "C" void kernel_launch(void* const* d_in, const int* in_sizes, int n_in,
                              void* d_out, int out_size, void* d_ws, size_t ws_size,
                              hipStream_t stream) {
    const float* x     = (const float*)d_in[0];   // [4,2048,1024]
    const float* w_qkv = (const float*)d_in[1];   // [1024,3072]
    const float* w_out = (const float*)d_in[2];   // [1024,1024]

    unsigned short* x_bf   = (unsigned short*)d_ws;
    unsigned short* wqkvT  = x_bf   + (size_t)MROWS * DIMM;
    unsigned short* woutT  = wqkvT  + (size_t)3 * DIMM * DIMM;
    unsigned short* qk_buf = woutT  + (size_t)DIMM * DIMM;           // [8192][QKP]
    unsigned short* vt     = qk_buf + (size_t)MROWS * QKP;           // [64][64][QKP]
    unsigned short* aout   = vt     + (size_t)64 * DH * QKP;         // [8192][1024]

    // 1. fused prep: conv + both weight transposes in one dispatch
    k_prep<<<8192 + 3072 + 1024, 256, 0, stream>>>(x, x_bf, w_qkv, wqkvT, w_out, woutT);

    // 2. QKV projection, 8-phase-style: Q(scaled)|K -> qk_buf, V^T -> vt
    k_gemm8<<<768, 512, 0, stream>>>(x_bf, wqkvT, qk_buf, vt);

    // 3. causal flash attention (R20 body)
    k_attn21<<<1024, 256, 0, stream>>>(qk_buf, vt, aout);

    // 4. output projection: [8192,1024] x [1024,1024] -> fp32 d_out
    k_gemm_bt<<<(MROWS / 128) * (DIMM / 128), 256, 0, stream>>>(
        aout, woutT, (float*)d_out, MROWS, DIMM, DIMM);
}

// Round 22
// 182.862 us; speedup vs baseline: 1.1019x; 1.1019x over previous
//
#include <hip/hip_runtime.h>
#include <hip/hip_bf16.h>
#include <stdint.h>

// Problem constants
#define SEQ  2048
#define DIMM 1024
#define NH   16
#define DH   64
#define NB   4
#define MROWS (NB*SEQ)   // 8192
#define QKP  2080        // padded row stride for qk/vt (breaks 4KB aliasing)

typedef __attribute__((ext_vector_type(8))) short bf16x8;
typedef __attribute__((ext_vector_type(4))) float f32x4;
typedef __attribute__((ext_vector_type(16))) float f32x16;

#define LOG2E 1.44269504088896340736f

__device__ __forceinline__ unsigned short f2bf(float f) {
    union { float f; uint32_t u; } c; c.f = f;
    uint32_t r = c.u + 0x7fff + ((c.u >> 16) & 1);
    return (unsigned short)(r >> 16);
}

__device__ __forceinline__ void gload_lds16(const void* g, void* lds) {
    __builtin_amdgcn_global_load_lds(
        (const __attribute__((address_space(1))) unsigned int*)(g),
        (__attribute__((address_space(3))) unsigned int*)(lds),
        16, 0, 0);
}

// ---- fused prep: x fp32->bf16 convert + both weight transposes ------------
__global__ __launch_bounds__(256) void k_prep(const float* __restrict__ x,
                                              unsigned short* __restrict__ x_bf,
                                              const float* __restrict__ w_qkv,
                                              unsigned short* __restrict__ wqkvT,
                                              const float* __restrict__ w_out,
                                              unsigned short* __restrict__ woutT) {
    __shared__ unsigned short tile[32][33];
    const int bid = blockIdx.x;
    if (bid < 8192) {
        int i = bid * 256 + threadIdx.x;
        float4 v = ((const float4*)x)[i];
        ushort4 o;
        o.x = f2bf(v.x); o.y = f2bf(v.y); o.z = f2bf(v.z); o.w = f2bf(v.w);
        ((ushort4*)x_bf)[i] = o;
        return;
    }
    const float* W;
    unsigned short* Wt;
    int tn, tk, N;
    if (bid < 8192 + 3072) {
        W = w_qkv; Wt = wqkvT; N = 3072;
        tn = (bid - 8192) % 96; tk = (bid - 8192) / 96;
    } else {
        W = w_out; Wt = woutT; N = 1024;
        tn = (bid - 11264) % 32; tk = (bid - 11264) / 32;
    }
    const int K = 1024;
    int lx = threadIdx.x & 31, ly = threadIdx.x >> 5;  // 32 x 8
    #pragma unroll
    for (int i = 0; i < 32; i += 8) {
        int k = tk * 32 + ly + i;
        int n = tn * 32 + lx;
        tile[ly + i][lx] = f2bf(W[(size_t)k * N + n]);
    }
    __syncthreads();
    int k2 = tk * 32 + lx;
    #pragma unroll
    for (int i = 0; i < 32; i += 8) {
        int n2 = tn * 32 + ly + i;
        Wt[(size_t)n2 * K + k2] = tile[lx][ly + i];
    }
}

// --------- C[M][N] = A[M][K] * Bt[N][K]^T   (bf16 in) -----------------------
// BK=64 + row&7 XOR LDS swizzle + bijective XCD block swizzle (R20-proven).
// MODE 0: plain fp32 C. MODE 1: fused QKV epilogue (Q*0.125*log2e|K -> qk,
// V -> vt transposed; strides QKP).
template<int MODE>
__global__ __launch_bounds__(256) void k_gemm_bt(const unsigned short* __restrict__ A,
                                                 const unsigned short* __restrict__ Bt,
                                                 void* __restrict__ Cv,
                                                 unsigned short* __restrict__ vtv,
                                                 int M, int N_, int K) {
    constexpr int BM = 128, BN = 128, BK = 64;
    __shared__ unsigned short lA[BM * BK];
    __shared__ unsigned short lB[BN * BK];
    const int ntile = N_ / BN;
    const int wgid = (blockIdx.x & 7) * (gridDim.x >> 3) + (blockIdx.x >> 3);
    const int tm = wgid / ntile;
    const int tn = wgid % ntile;
    const int t = threadIdx.x;
    const int w = t >> 6, l = t & 63;
    const int wr = w >> 1, wc = w & 1;

    const unsigned short* Abase = A + (size_t)tm * BM * K;
    const unsigned short* Bbase = Bt + (size_t)tn * BN * K;

    f32x4 acc[4][4] = {};
    const int rswz = (l & 7) << 4;

    for (int k0 = 0; k0 < K; k0 += BK) {
        __syncthreads();
        #pragma unroll
        for (int i = 0; i < 4; ++i) {
            const int o  = i * 4096 + t * 16;
            const int so = o ^ (((o >> 7) & 7) << 4);
            gload_lds16((const char*)(Abase + (size_t)(so >> 7) * K + k0) + (so & 127),
                        (char*)lA + i * 4096 + w * 1024);
            gload_lds16((const char*)(Bbase + (size_t)(so >> 7) * K + k0) + (so & 127),
                        (char*)lB + i * 4096 + w * 1024);
        }
        __syncthreads();

        #pragma unroll
        for (int kk = 0; kk < 2; ++kk) {
            bf16x8 af[4], bfv[4];
            #pragma unroll
            for (int i = 0; i < 4; ++i) {
                const int ea = ((wr * 64 + i * 16 + (l & 15)) << 7) + kk * 64 + ((l >> 4) << 4);
                af[i] = *(const bf16x8*)((const char*)lA + (ea ^ rswz));
            }
            #pragma unroll
            for (int j = 0; j < 4; ++j) {
                const int eb = ((wc * 64 + j * 16 + (l & 15)) << 7) + kk * 64 + ((l >> 4) << 4);
                bfv[j] = *(const bf16x8*)((const char*)lB + (eb ^ rswz));
            }
            #pragma unroll
            for (int i = 0; i < 4; ++i)
                #pragma unroll
                for (int j = 0; j < 4; ++j)
                    acc[i][j] = __builtin_amdgcn_mfma_f32_16x16x32_bf16(af[i], bfv[j], acc[i][j], 0, 0, 0);
        }
    }

    const int row0 = tm * BM + wr * 64 + (l >> 4) * 4;
    const int col0 = tn * BN + wc * 64 + (l & 15);

    if (MODE == 0) {
        float* Cf = (float*)Cv;
        #pragma unroll
        for (int i = 0; i < 4; ++i)
            #pragma unroll
            for (int j = 0; j < 4; ++j)
                #pragma unroll
                for (int r = 0; r < 4; ++r)
                    Cf[(size_t)(row0 + i * 16 + r) * N_ + (col0 + j * 16)] = acc[i][j][r];
    } else if (tn < 16) {
        const float cs = (tn < 8) ? 0.125f * LOG2E : 1.0f;
        unsigned short* qk = (unsigned short*)Cv;
        #pragma unroll
        for (int i = 0; i < 4; ++i)
            #pragma unroll
            for (int j = 0; j < 4; ++j)
                #pragma unroll
                for (int r = 0; r < 4; ++r)
                    qk[(size_t)(row0 + i * 16 + r) * QKP + (col0 + j * 16)] = f2bf(acc[i][j][r] * cs);
    } else {
        #pragma unroll
        for (int i = 0; i < 4; ++i) {
            const int rbase = row0 + i * 16;
            const int bq = rbase >> 11;
            const int n0 = rbase & 2047;
            #pragma unroll
            for (int j = 0; j < 4; ++j) {
                const int c = col0 + j * 16 - 2048;
                const int hh = c >> 6, dd = c & 63;
                uint2 u;
                u.x = (unsigned int)f2bf(acc[i][j][0]) | ((unsigned int)f2bf(acc[i][j][1]) << 16);
                u.y = (unsigned int)f2bf(acc[i][j][2]) | ((unsigned int)f2bf(acc[i][j][3]) << 16);
                *(uint2*)(vtv + ((size_t)(bq * 16 + hh) * 64 + dd) * QKP + n0) = u;
            }
        }
    }
}

// -- causal flash attention (v22: LDS-staged K/V, block-shared kv loop) ------
// Block = (bh, pair): 4 waves x 32 q-rows = 128-row chunk; two chunks
// sequentially (heavy 15-p, then p) -> uniform 36 block-tiles. Per kv-tile,
// K(8KB)+V(8KB) staged ONCE per block via global_load_lds (coalesced,
// pre-swizzled source) and read back with XOR-swizzled ds_read_b128 (T2,
// R11-verified). Replaces 2048 gathered line-transactions/wave-tile with
// coalesced staging + 4x reuse. Softmax/pack/PV math = R16 body.
__global__ __launch_bounds__(256, 2) void k_attn22(const unsigned short* __restrict__ qk,
                                                   const unsigned short* __restrict__ vt,
                                                   unsigned short* __restrict__ out) {
    // bijective XCD swizzle: 512 blocks = 8 XCD x 64
    const int wid = (blockIdx.x & 7) * 64 + (blockIdx.x >> 3);
    const int bh = wid >> 3;                  // 0..63
    const int pair = wid & 7;                 // 0..7
    const int b = bh >> 4, h = bh & 15;
    const int t = threadIdx.x;
    const int w = t >> 6, l = t & 63;
    const int l31 = l & 31, hi = l >> 5;

    __shared__ unsigned short Kl[2][64 * 64]; // 2 x 8 KB
    __shared__ unsigned short Vl[2][64 * 64]; // 2 x 8 KB

    const unsigned short* qp = qk + (size_t)(b * SEQ) * QKP + h * 64;
    unsigned short* op = out + (size_t)(b * SEQ) * DIMM + h * 64;
    const char* kbase = (const char*)(qk + (size_t)(b * SEQ) * QKP + 1024 + h * 64);
    const char* vbase = (const char*)(vt + (size_t)bh * 64 * QKP);

    const int rswz = (l & 7) << 4;
    union U8 { uint32_t u[4]; bf16x8 v; };

    // stage kv tile (64 rows K + 64 rows V^T, 128B rows) into buffer bs
    auto STAGE = [&](int kv0, int bs) {
        #pragma unroll
        for (int i = 0; i < 2; ++i) {
            const int o  = i * 4096 + t * 16;
            const int so = o ^ (((o >> 7) & 7) << 4);
            const int row = so >> 7, cb = so & 127;
            gload_lds16(kbase + (size_t)(kv0 + row) * (QKP * 2) + cb,
                        (char*)Kl[bs] + i * 4096 + w * 1024);
            gload_lds16(vbase + (size_t)row * (QKP * 2) + kv0 * 2 + cb,
                        (char*)Vl[bs] + i * 4096 + w * 1024);
        }
    };

    for (int ci = 0; ci < 2; ++ci) {
        const int c = ci ? pair : 15 - pair;       // heavy first, then light
        const int q0w = c * 128 + w * 32;          // wave's first q row
        const int qrow = q0w + l31;                // this lane's q row
        const int ntw = (q0w >> 6) + 1;            // wave's kv-tile count
        const int ntb = c * 2 + 2;                 // block's kv-tile count

        // Q as B-operand (global, once per chunk; prescaled 1/8*log2e)
        bf16x8 qf[4];
        #pragma unroll
        for (int m = 0; m < 4; ++m)
            qf[m] = *(const bf16x8*)(qp + (size_t)(q0w + l31) * QKP + m * 16 + hi * 8);

        f32x16 accO0 = {}, accO1 = {};
        float m_run = -INFINITY, l_run = 0.f;

        STAGE(0, 0);
        __syncthreads();   // implicit vmcnt(0) drain -> buf0 ready

        for (int kt = 0; kt < ntb; ++kt) {
            if (kt + 1 < ntb) STAGE((kt + 1) * 64, (kt + 1) & 1);

            if (kt < ntw) {
                const int kv0 = kt * 64;
                const bool msk = (kt == ntw - 1);
                const char* kl = (const char*)Kl[kt & 1];
                const char* vl = (const char*)Vl[kt & 1];

                // K fragments from LDS (row f*32+l31, col m*16+hi*8)
                bf16x8 kf[2][4];
                #pragma unroll
                for (int f = 0; f < 2; ++f)
                    #pragma unroll
                    for (int m = 0; m < 4; ++m) {
                        const int ea = ((f * 32 + l31) << 7) + m * 32 + hi * 16;
                        kf[f][m] = *(const bf16x8*)(kl + (ea ^ rswz));
                    }

                // QK^T swapped -> S^T
                f32x16 s0 = {}, s1 = {};
                __builtin_amdgcn_s_setprio(1);
                #pragma unroll
                for (int m = 0; m < 4; ++m) {
                    s0 = __builtin_amdgcn_mfma_f32_32x32x16_bf16(kf[0][m], qf[m], s0, 0, 0, 0);
                    s1 = __builtin_amdgcn_mfma_f32_32x32x16_bf16(kf[1][m], qf[m], s1, 0, 0, 0);
                }
                __builtin_amdgcn_s_setprio(0);

                // V^T fragments from LDS (row f*32+l31 = d, col m*16+hi*8 = kv)
                bf16x8 vf0[4], vf1[4];
                #pragma unroll
                for (int m = 0; m < 4; ++m) {
                    const int e0 = (l31 << 7) + m * 32 + hi * 16;
                    const int e1 = ((32 + l31) << 7) + m * 32 + hi * 16;
                    vf0[m] = *(const bf16x8*)(vl + (e0 ^ rswz));
                    vf1[m] = *(const bf16x8*)(vl + (e1 ^ rswz));
                }

                // ---- in-lane online softmax, exp2 domain, defer-max ----
                float tmax = -1e30f;
                #pragma unroll
                for (int r = 0; r < 16; ++r) {
                    float v0 = s0[r];
                    float v1 = s1[r];
                    if (msk) {
                        const int crow = (r & 3) + 8 * (r >> 2) + 4 * hi;
                        if (kv0 + crow > qrow)      v0 = -1e30f;
                        if (kv0 + 32 + crow > qrow) v1 = -1e30f;
                        s0[r] = v0; s1[r] = v1;
                    }
                    tmax = fmaxf(tmax, fmaxf(v0, v1));
                }
                tmax = fmaxf(tmax, __shfl_xor(tmax, 32));
                const bool defer = __all(tmax <= m_run + 8.0f);
                float fct = 1.0f;
                if (!defer) {
                    const float mnew = fmaxf(m_run, tmax);
                    fct = exp2f(m_run - mnew);
                    m_run = mnew;
                    #pragma unroll
                    for (int r = 0; r < 16; ++r) { accO0[r] *= fct; accO1[r] *= fct; }
                }
                float ps = 0.f;
                #pragma unroll
                for (int r = 0; r < 16; ++r) {
                    float p0 = exp2f(s0[r] - m_run);
                    float p1 = exp2f(s1[r] - m_run);
                    s0[r] = p0; s1[r] = p1;
                    ps += p0 + p1;
                }
                ps += __shfl_xor(ps, 32);
                l_run = l_run * fct + ps;

                // ---- P -> bf16 pack + permlane + PV (O^T) ----
                uint32_t pw0[8], pw1[8];
                #pragma unroll
                for (int i = 0; i < 8; ++i) {
                    asm("v_cvt_pk_bf16_f32 %0, %1, %2" : "=v"(pw0[i]) : "v"(s0[2*i]), "v"(s0[2*i+1]));
                    asm("v_cvt_pk_bf16_f32 %0, %1, %2" : "=v"(pw1[i]) : "v"(s1[2*i]), "v"(s1[2*i+1]));
                }
                __builtin_amdgcn_s_setprio(1);
                #define PVCHUNK(PW, BASE, VF0, VF1) do {                                     \
                    uint32_t a0 = PW[BASE+0], b0 = PW[BASE+2];                               \
                    uint32_t a1 = PW[BASE+1], b1 = PW[BASE+3];                               \
                    asm("v_permlane32_swap_b32 %0, %1" : "+v"(a0), "+v"(b0));                \
                    asm("v_permlane32_swap_b32 %0, %1" : "+v"(a1), "+v"(b1));                \
                    U8 pb; pb.u[0] = a0; pb.u[1] = a1; pb.u[2] = b0; pb.u[3] = b1;           \
                    accO0 = __builtin_amdgcn_mfma_f32_32x32x16_bf16(VF0, pb.v, accO0, 0, 0, 0); \
                    accO1 = __builtin_amdgcn_mfma_f32_32x32x16_bf16(VF1, pb.v, accO1, 0, 0, 0); \
                } while (0)
                PVCHUNK(pw0, 0, vf0[0], vf1[0]);
                PVCHUNK(pw0, 4, vf0[1], vf1[1]);
                PVCHUNK(pw1, 0, vf0[2], vf1[2]);
                PVCHUNK(pw1, 4, vf0[3], vf1[3]);
                #undef PVCHUNK
                __builtin_amdgcn_s_setprio(0);
            }

            __syncthreads();   // all reads of buf[kt&1] done; STAGE(kt+1) drained
        }

        // epilogue: lane holds O[q = q0w+l31][d = crow + {0,32}], own l_run
        const float inv = 1.0f / l_run;
        unsigned short* orow = op + (size_t)(q0w + l31) * DIMM;
        #pragma unroll
        for (int g = 0; g < 4; ++g) {
            uint2 u0, u1;
            float a0 = accO0[4*g+0] * inv, a1 = accO0[4*g+1] * inv;
            float a2 = accO0[4*g+2] * inv, a3 = accO0[4*g+3] * inv;
            float c0 = accO1[4*g+0] * inv, c1 = accO1[4*g+1] * inv;
            float c2 = accO1[4*g+2] * inv, c3 = accO1[4*g+3] * inv;
            asm("v_cvt_pk_bf16_f32 %0, %1, %2" : "=v"(u0.x) : "v"(a0), "v"(a1));
            asm("v_cvt_pk_bf16_f32 %0, %1, %2" : "=v"(u0.y) : "v"(a2), "v"(a3));
            asm("v_cvt_pk_bf16_f32 %0, %1, %2" : "=v"(u1.x) : "v"(c0), "v"(c1));
            asm("v_cvt_pk_bf16_f32 %0, %1, %2" : "=v"(u1.y) : "v"(c2), "v"(c3));
            *(uint2*)(orow + 8*g + 4*hi)      = u0;   // d = 8g+4hi .. +3
            *(uint2*)(orow + 32 + 8*g + 4*hi) = u1;   // d = 32+8g+4hi .. +3
        }
    }
}

// ---------------------------------------------------------------------------
extern "C" void kernel_launch(void* const* d_in, const int* in_sizes, int n_in,
                              void* d_out, int out_size, void* d_ws, size_t ws_size,
                              hipStream_t stream) {
    const float* x     = (const float*)d_in[0];   // [4,2048,1024]
    const float* w_qkv = (const float*)d_in[1];   // [1024,3072]
    const float* w_out = (const float*)d_in[2];   // [1024,1024]

    unsigned short* x_bf   = (unsigned short*)d_ws;
    unsigned short* wqkvT  = x_bf   + (size_t)MROWS * DIMM;
    unsigned short* woutT  = wqkvT  + (size_t)3 * DIMM * DIMM;
    unsigned short* qk_buf = woutT  + (size_t)DIMM * DIMM;           // [8192][QKP]
    unsigned short* vt     = qk_buf + (size_t)MROWS * QKP;           // [64][64][QKP]
    unsigned short* aout   = vt     + (size_t)64 * DH * QKP;         // [8192][1024]

    // 1. fused prep: conv + both weight transposes in one dispatch
    k_prep<<<8192 + 3072 + 1024, 256, 0, stream>>>(x, x_bf, w_qkv, wqkvT, w_out, woutT);

    // 2. QKV projection (R20-proven): Q(scaled)|K -> qk_buf, V^T -> vt
    k_gemm_bt<1><<<(MROWS / 128) * (3 * DIMM / 128), 256, 0, stream>>>(
        x_bf, wqkvT, qk_buf, vt, MROWS, 3 * DIMM, DIMM);

    // 3. causal flash attention (LDS-staged K/V, block-shared kv loop)
    k_attn22<<<NB * NH * 8, 256, 0, stream>>>(qk_buf, vt, aout);

    // 4. output projection: [8192,1024] x [1024,1024] -> fp32 d_out
    k_gemm_bt<0><<<(MROWS / 128) * (DIMM / 128), 256, 0, stream>>>(
        aout, woutT, d_out, nullptr, MROWS, DIMM, DIMM);
}

// Round 23
// 177.887 us; speedup vs baseline: 1.1327x; 1.0280x over previous
//
#include <hip/hip_runtime.h>
#include <hip/hip_bf16.h>
#include <stdint.h>

// Problem constants
#define SEQ  2048
#define DIMM 1024
#define NH   16
#define DH   64
#define NB   4
#define MROWS (NB*SEQ)   // 8192
#define QKP  2080        // padded row stride for qk/vt (breaks 4KB aliasing)

typedef __attribute__((ext_vector_type(8))) short bf16x8;
typedef __attribute__((ext_vector_type(4))) float f32x4;
typedef __attribute__((ext_vector_type(16))) float f32x16;

#define LOG2E 1.44269504088896340736f

template<bool B> struct BoolC { static constexpr bool value = B; };

__device__ __forceinline__ unsigned short f2bf(float f) {
    union { float f; uint32_t u; } c; c.f = f;
    uint32_t r = c.u + 0x7fff + ((c.u >> 16) & 1);
    return (unsigned short)(r >> 16);
}

__device__ __forceinline__ void gload_lds16(const void* g, void* lds) {
    __builtin_amdgcn_global_load_lds(
        (const __attribute__((address_space(1))) unsigned int*)(g),
        (__attribute__((address_space(3))) unsigned int*)(lds),
        16, 0, 0);
}

// ---- fused prep: x fp32->bf16 convert + both weight transposes ------------
__global__ __launch_bounds__(256) void k_prep(const float* __restrict__ x,
                                              unsigned short* __restrict__ x_bf,
                                              const float* __restrict__ w_qkv,
                                              unsigned short* __restrict__ wqkvT,
                                              const float* __restrict__ w_out,
                                              unsigned short* __restrict__ woutT) {
    __shared__ unsigned short tile[32][33];
    const int bid = blockIdx.x;
    if (bid < 8192) {
        int i = bid * 256 + threadIdx.x;
        float4 v = ((const float4*)x)[i];
        ushort4 o;
        o.x = f2bf(v.x); o.y = f2bf(v.y); o.z = f2bf(v.z); o.w = f2bf(v.w);
        ((ushort4*)x_bf)[i] = o;
        return;
    }
    const float* W;
    unsigned short* Wt;
    int tn, tk, N;
    if (bid < 8192 + 3072) {
        W = w_qkv; Wt = wqkvT; N = 3072;
        tn = (bid - 8192) % 96; tk = (bid - 8192) / 96;
    } else {
        W = w_out; Wt = woutT; N = 1024;
        tn = (bid - 11264) % 32; tk = (bid - 11264) / 32;
    }
    const int K = 1024;
    int lx = threadIdx.x & 31, ly = threadIdx.x >> 5;  // 32 x 8
    #pragma unroll
    for (int i = 0; i < 32; i += 8) {
        int k = tk * 32 + ly + i;
        int n = tn * 32 + lx;
        tile[ly + i][lx] = f2bf(W[(size_t)k * N + n]);
    }
    __syncthreads();
    int k2 = tk * 32 + lx;
    #pragma unroll
    for (int i = 0; i < 32; i += 8) {
        int n2 = tn * 32 + ly + i;
        Wt[(size_t)n2 * K + k2] = tile[lx][ly + i];
    }
}

// --------- C[M][N] = A[M][K] * Bt[N][K]^T   (bf16 in) -----------------------
// BK=64 + row&7 XOR LDS swizzle + bijective XCD block swizzle (R20-proven).
// MODE 0: plain fp32 C. MODE 1: fused QKV epilogue (Q*0.125*log2e|K -> qk,
// V -> vt transposed; strides QKP).
template<int MODE>
__global__ __launch_bounds__(256) void k_gemm_bt(const unsigned short* __restrict__ A,
                                                 const unsigned short* __restrict__ Bt,
                                                 void* __restrict__ Cv,
                                                 unsigned short* __restrict__ vtv,
                                                 int M, int N_, int K) {
    constexpr int BM = 128, BN = 128, BK = 64;
    __shared__ unsigned short lA[BM * BK];
    __shared__ unsigned short lB[BN * BK];
    const int ntile = N_ / BN;
    const int wgid = (blockIdx.x & 7) * (gridDim.x >> 3) + (blockIdx.x >> 3);
    const int tm = wgid / ntile;
    const int tn = wgid % ntile;
    const int t = threadIdx.x;
    const int w = t >> 6, l = t & 63;
    const int wr = w >> 1, wc = w & 1;

    const unsigned short* Abase = A + (size_t)tm * BM * K;
    const unsigned short* Bbase = Bt + (size_t)tn * BN * K;

    f32x4 acc[4][4] = {};
    const int rswz = (l & 7) << 4;

    for (int k0 = 0; k0 < K; k0 += BK) {
        __syncthreads();
        #pragma unroll
        for (int i = 0; i < 4; ++i) {
            const int o  = i * 4096 + t * 16;
            const int so = o ^ (((o >> 7) & 7) << 4);
            gload_lds16((const char*)(Abase + (size_t)(so >> 7) * K + k0) + (so & 127),
                        (char*)lA + i * 4096 + w * 1024);
            gload_lds16((const char*)(Bbase + (size_t)(so >> 7) * K + k0) + (so & 127),
                        (char*)lB + i * 4096 + w * 1024);
        }
        __syncthreads();

        #pragma unroll
        for (int kk = 0; kk < 2; ++kk) {
            bf16x8 af[4], bfv[4];
            #pragma unroll
            for (int i = 0; i < 4; ++i) {
                const int ea = ((wr * 64 + i * 16 + (l & 15)) << 7) + kk * 64 + ((l >> 4) << 4);
                af[i] = *(const bf16x8*)((const char*)lA + (ea ^ rswz));
            }
            #pragma unroll
            for (int j = 0; j < 4; ++j) {
                const int eb = ((wc * 64 + j * 16 + (l & 15)) << 7) + kk * 64 + ((l >> 4) << 4);
                bfv[j] = *(const bf16x8*)((const char*)lB + (eb ^ rswz));
            }
            #pragma unroll
            for (int i = 0; i < 4; ++i)
                #pragma unroll
                for (int j = 0; j < 4; ++j)
                    acc[i][j] = __builtin_amdgcn_mfma_f32_16x16x32_bf16(af[i], bfv[j], acc[i][j], 0, 0, 0);
        }
    }

    const int row0 = tm * BM + wr * 64 + (l >> 4) * 4;
    const int col0 = tn * BN + wc * 64 + (l & 15);

    if (MODE == 0) {
        float* Cf = (float*)Cv;
        #pragma unroll
        for (int i = 0; i < 4; ++i)
            #pragma unroll
            for (int j = 0; j < 4; ++j)
                #pragma unroll
                for (int r = 0; r < 4; ++r)
                    Cf[(size_t)(row0 + i * 16 + r) * N_ + (col0 + j * 16)] = acc[i][j][r];
    } else if (tn < 16) {
        const float cs = (tn < 8) ? 0.125f * LOG2E : 1.0f;
        unsigned short* qk = (unsigned short*)Cv;
        #pragma unroll
        for (int i = 0; i < 4; ++i)
            #pragma unroll
            for (int j = 0; j < 4; ++j)
                #pragma unroll
                for (int r = 0; r < 4; ++r)
                    qk[(size_t)(row0 + i * 16 + r) * QKP + (col0 + j * 16)] = f2bf(acc[i][j][r] * cs);
    } else {
        #pragma unroll
        for (int i = 0; i < 4; ++i) {
            const int rbase = row0 + i * 16;
            const int bq = rbase >> 11;
            const int n0 = rbase & 2047;
            #pragma unroll
            for (int j = 0; j < 4; ++j) {
                const int c = col0 + j * 16 - 2048;
                const int hh = c >> 6, dd = c & 63;
                uint2 u;
                u.x = (unsigned int)f2bf(acc[i][j][0]) | ((unsigned int)f2bf(acc[i][j][1]) << 16);
                u.y = (unsigned int)f2bf(acc[i][j][2]) | ((unsigned int)f2bf(acc[i][j][3]) << 16);
                *(uint2*)(vtv + ((size_t)(bq * 16 + hh) * 64 + dd) * QKP + n0) = u;
            }
        }
    }
}

// -- causal flash attention (v23: R22 LDS-staged + compile-time mask split) --
// Block = (bh, pair): 4 waves x 32 q-rows = 128-row chunk; two chunks
// sequentially (heavy 15-p, then p). K/V staged once per block per kv-tile
// via global_load_lds; XOR-swizzled ds_read. Mask now compile-time: unmasked
// body for kt < ntw-1, masked once (R19-proven; removes 64 cmp+cndmask/tile).
__global__ __launch_bounds__(256, 2) void k_attn23(const unsigned short* __restrict__ qk,
                                                   const unsigned short* __restrict__ vt,
                                                   unsigned short* __restrict__ out) {
    // bijective XCD swizzle: 512 blocks = 8 XCD x 64
    const int wid = (blockIdx.x & 7) * 64 + (blockIdx.x >> 3);
    const int bh = wid >> 3;                  // 0..63
    const int pair = wid & 7;                 // 0..7
    const int b = bh >> 4, h = bh & 15;
    const int t = threadIdx.x;
    const int w = t >> 6, l = t & 63;
    const int l31 = l & 31, hi = l >> 5;

    __shared__ unsigned short Kl[2][64 * 64]; // 2 x 8 KB
    __shared__ unsigned short Vl[2][64 * 64]; // 2 x 8 KB

    const unsigned short* qp = qk + (size_t)(b * SEQ) * QKP + h * 64;
    unsigned short* op = out + (size_t)(b * SEQ) * DIMM + h * 64;
    const char* kbase = (const char*)(qk + (size_t)(b * SEQ) * QKP + 1024 + h * 64);
    const char* vbase = (const char*)(vt + (size_t)bh * 64 * QKP);

    const int rswz = (l & 7) << 4;
    union U8 { uint32_t u[4]; bf16x8 v; };

    // stage kv tile (64 rows K + 64 rows V^T, 128B rows) into buffer bs
    auto STAGE = [&](int kv0, int bs) {
        #pragma unroll
        for (int i = 0; i < 2; ++i) {
            const int o  = i * 4096 + t * 16;
            const int so = o ^ (((o >> 7) & 7) << 4);
            const int row = so >> 7, cb = so & 127;
            gload_lds16(kbase + (size_t)(kv0 + row) * (QKP * 2) + cb,
                        (char*)Kl[bs] + i * 4096 + w * 1024);
            gload_lds16(vbase + (size_t)row * (QKP * 2) + kv0 * 2 + cb,
                        (char*)Vl[bs] + i * 4096 + w * 1024);
        }
    };

    for (int ci = 0; ci < 2; ++ci) {
        const int c = ci ? pair : 15 - pair;       // heavy first, then light
        const int q0w = c * 128 + w * 32;          // wave's first q row
        const int qrow = q0w + l31;                // this lane's q row
        const int ntw = (q0w >> 6) + 1;            // wave's kv-tile count
        const int ntb = c * 2 + 2;                 // block's kv-tile count

        // Q as B-operand (global, once per chunk; prescaled 1/8*log2e)
        bf16x8 qf[4];
        #pragma unroll
        for (int m = 0; m < 4; ++m)
            qf[m] = *(const bf16x8*)(qp + (size_t)(q0w + l31) * QKP + m * 16 + hi * 8);

        f32x16 accO0 = {}, accO1 = {};
        float m_run = -INFINITY, l_run = 0.f;

        STAGE(0, 0);
        __syncthreads();   // implicit vmcnt(0) drain -> buf0 ready

        // one kv-tile of compute; MSK is compile-time
        auto tile = [&](int kt, auto mskc) {
            constexpr bool MSK = decltype(mskc)::value;
            const int kv0 = kt * 64;
            const char* kl = (const char*)Kl[kt & 1];
            const char* vl = (const char*)Vl[kt & 1];

            // K fragments from LDS (row f*32+l31, col m*16+hi*8)
            bf16x8 kf[2][4];
            #pragma unroll
            for (int f = 0; f < 2; ++f)
                #pragma unroll
                for (int m = 0; m < 4; ++m) {
                    const int ea = ((f * 32 + l31) << 7) + m * 32 + hi * 16;
                    kf[f][m] = *(const bf16x8*)(kl + (ea ^ rswz));
                }

            // QK^T swapped -> S^T
            f32x16 s0 = {}, s1 = {};
            __builtin_amdgcn_s_setprio(1);
            #pragma unroll
            for (int m = 0; m < 4; ++m) {
                s0 = __builtin_amdgcn_mfma_f32_32x32x16_bf16(kf[0][m], qf[m], s0, 0, 0, 0);
                s1 = __builtin_amdgcn_mfma_f32_32x32x16_bf16(kf[1][m], qf[m], s1, 0, 0, 0);
            }
            __builtin_amdgcn_s_setprio(0);

            // V^T fragments from LDS (row = d, col = kv)
            bf16x8 vf0[4], vf1[4];
            #pragma unroll
            for (int m = 0; m < 4; ++m) {
                const int e0 = (l31 << 7) + m * 32 + hi * 16;
                const int e1 = ((32 + l31) << 7) + m * 32 + hi * 16;
                vf0[m] = *(const bf16x8*)(vl + (e0 ^ rswz));
                vf1[m] = *(const bf16x8*)(vl + (e1 ^ rswz));
            }

            // ---- in-lane online softmax, exp2 domain, defer-max ----
            float tmax = -1e30f;
            #pragma unroll
            for (int r = 0; r < 16; ++r) {
                float v0 = s0[r];
                float v1 = s1[r];
                if (MSK) {
                    const int crow = (r & 3) + 8 * (r >> 2) + 4 * hi;
                    if (kv0 + crow > qrow)      v0 = -1e30f;
                    if (kv0 + 32 + crow > qrow) v1 = -1e30f;
                    s0[r] = v0; s1[r] = v1;
                }
                tmax = fmaxf(tmax, fmaxf(v0, v1));
            }
            tmax = fmaxf(tmax, __shfl_xor(tmax, 32));
            const bool defer = __all(tmax <= m_run + 8.0f);
            float fct = 1.0f;
            if (!defer) {
                const float mnew = fmaxf(m_run, tmax);
                fct = exp2f(m_run - mnew);
                m_run = mnew;
                #pragma unroll
                for (int r = 0; r < 16; ++r) { accO0[r] *= fct; accO1[r] *= fct; }
            }
            float ps = 0.f;
            #pragma unroll
            for (int r = 0; r < 16; ++r) {
                float p0 = exp2f(s0[r] - m_run);
                float p1 = exp2f(s1[r] - m_run);
                s0[r] = p0; s1[r] = p1;
                ps += p0 + p1;
            }
            ps += __shfl_xor(ps, 32);
            l_run = l_run * fct + ps;

            // ---- P -> bf16 pack + permlane + PV (O^T) ----
            uint32_t pw0[8], pw1[8];
            #pragma unroll
            for (int i = 0; i < 8; ++i) {
                asm("v_cvt_pk_bf16_f32 %0, %1, %2" : "=v"(pw0[i]) : "v"(s0[2*i]), "v"(s0[2*i+1]));
                asm("v_cvt_pk_bf16_f32 %0, %1, %2" : "=v"(pw1[i]) : "v"(s1[2*i]), "v"(s1[2*i+1]));
            }
            __builtin_amdgcn_s_setprio(1);
            #define PVCHUNK(PW, BASE, VF0, VF1) do {                                     \
                uint32_t a0 = PW[BASE+0], b0 = PW[BASE+2];                               \
                uint32_t a1 = PW[BASE+1], b1 = PW[BASE+3];                               \
                asm("v_permlane32_swap_b32 %0, %1" : "+v"(a0), "+v"(b0));                \
                asm("v_permlane32_swap_b32 %0, %1" : "+v"(a1), "+v"(b1));                \
                U8 pb; pb.u[0] = a0; pb.u[1] = a1; pb.u[2] = b0; pb.u[3] = b1;           \
                accO0 = __builtin_amdgcn_mfma_f32_32x32x16_bf16(VF0, pb.v, accO0, 0, 0, 0); \
                accO1 = __builtin_amdgcn_mfma_f32_32x32x16_bf16(VF1, pb.v, accO1, 0, 0, 0); \
            } while (0)
            PVCHUNK(pw0, 0, vf0[0], vf1[0]);
            PVCHUNK(pw0, 4, vf0[1], vf1[1]);
            PVCHUNK(pw1, 0, vf0[2], vf1[2]);
            PVCHUNK(pw1, 4, vf0[3], vf1[3]);
            #undef PVCHUNK
            __builtin_amdgcn_s_setprio(0);
        };

        for (int kt = 0; kt < ntb; ++kt) {
            if (kt + 1 < ntb) STAGE((kt + 1) * 64, (kt + 1) & 1);

            if (kt < ntw - 1)       tile(kt, BoolC<false>{});
            else if (kt == ntw - 1) tile(kt, BoolC<true>{});

            __syncthreads();   // all reads of buf[kt&1] done; STAGE(kt+1) drained
        }

        // epilogue: lane holds O[q = q0w+l31][d = crow + {0,32}], own l_run
        const float inv = 1.0f / l_run;
        unsigned short* orow = op + (size_t)(q0w + l31) * DIMM;
        #pragma unroll
        for (int g = 0; g < 4; ++g) {
            uint2 u0, u1;
            float a0 = accO0[4*g+0] * inv, a1 = accO0[4*g+1] * inv;
            float a2 = accO0[4*g+2] * inv, a3 = accO0[4*g+3] * inv;
            float c0 = accO1[4*g+0] * inv, c1 = accO1[4*g+1] * inv;
            float c2 = accO1[4*g+2] * inv, c3 = accO1[4*g+3] * inv;
            asm("v_cvt_pk_bf16_f32 %0, %1, %2" : "=v"(u0.x) : "v"(a0), "v"(a1));
            asm("v_cvt_pk_bf16_f32 %0, %1, %2" : "=v"(u0.y) : "v"(a2), "v"(a3));
            asm("v_cvt_pk_bf16_f32 %0, %1, %2" : "=v"(u1.x) : "v"(c0), "v"(c1));
            asm("v_cvt_pk_bf16_f32 %0, %1, %2" : "=v"(u1.y) : "v"(c2), "v"(c3));
            *(uint2*)(orow + 8*g + 4*hi)      = u0;   // d = 8g+4hi .. +3
            *(uint2*)(orow + 32 + 8*g + 4*hi) = u1;   // d = 32+8g+4hi .. +3
        }
    }
}

// ---------------------------------------------------------------------------
extern "C" void kernel_launch(void* const* d_in, const int* in_sizes, int n_in,
                              void* d_out, int out_size, void* d_ws, size_t ws_size,
                              hipStream_t stream) {
    const float* x     = (const float*)d_in[0];   // [4,2048,1024]
    const float* w_qkv = (const float*)d_in[1];   // [1024,3072]
    const float* w_out = (const float*)d_in[2];   // [1024,1024]

    unsigned short* x_bf   = (unsigned short*)d_ws;
    unsigned short* wqkvT  = x_bf   + (size_t)MROWS * DIMM;
    unsigned short* woutT  = wqkvT  + (size_t)3 * DIMM * DIMM;
    unsigned short* qk_buf = woutT  + (size_t)DIMM * DIMM;           // [8192][QKP]
    unsigned short* vt     = qk_buf + (size_t)MROWS * QKP;           // [64][64][QKP]
    unsigned short* aout   = vt     + (size_t)64 * DH * QKP;         // [8192][1024]

    // 1. fused prep: conv + both weight transposes in one dispatch
    k_prep<<<8192 + 3072 + 1024, 256, 0, stream>>>(x, x_bf, w_qkv, wqkvT, w_out, woutT);

    // 2. QKV projection (R20-proven): Q(scaled)|K -> qk_buf, V^T -> vt
    k_gemm_bt<1><<<(MROWS / 128) * (3 * DIMM / 128), 256, 0, stream>>>(
        x_bf, wqkvT, qk_buf, vt, MROWS, 3 * DIMM, DIMM);

    // 3. causal flash attention (LDS-staged + compile-time mask split)
    k_attn23<<<NB * NH * 8, 256, 0, stream>>>(qk_buf, vt, aout);

    // 4. output projection: [8192,1024] x [1024,1024] -> fp32 d_out
    k_gemm_bt<0><<<(MROWS / 128) * (DIMM / 128), 256, 0, stream>>>(
        aout, woutT, d_out, nullptr, MROWS, DIMM, DIMM);
}

// Round 24
// 175.435 us; speedup vs baseline: 1.1485x; 1.0140x over previous
//
#include <hip/hip_runtime.h>
#include <hip/hip_bf16.h>
#include <stdint.h>

// Problem constants
#define SEQ  2048
#define DIMM 1024
#define NH   16
#define DH   64
#define NB   4
#define MROWS (NB*SEQ)   // 8192
#define QKP  2080        // padded row stride for qk/vt (breaks 4KB aliasing)

typedef __attribute__((ext_vector_type(8))) short bf16x8;
typedef __attribute__((ext_vector_type(4))) float f32x4;
typedef __attribute__((ext_vector_type(16))) float f32x16;

#define LOG2E 1.44269504088896340736f

template<bool B> struct BoolC { static constexpr bool value = B; };

__device__ __forceinline__ unsigned short f2bf(float f) {
    union { float f; uint32_t u; } c; c.f = f;
    uint32_t r = c.u + 0x7fff + ((c.u >> 16) & 1);
    return (unsigned short)(r >> 16);
}

__device__ __forceinline__ void gload_lds16(const void* g, void* lds) {
    __builtin_amdgcn_global_load_lds(
        (const __attribute__((address_space(1))) unsigned int*)(g),
        (__attribute__((address_space(3))) unsigned int*)(lds),
        16, 0, 0);
}

// ---- fused prep: x fp32->bf16 convert + both weight transposes ------------
__global__ __launch_bounds__(256) void k_prep(const float* __restrict__ x,
                                              unsigned short* __restrict__ x_bf,
                                              const float* __restrict__ w_qkv,
                                              unsigned short* __restrict__ wqkvT,
                                              const float* __restrict__ w_out,
                                              unsigned short* __restrict__ woutT) {
    __shared__ unsigned short tile[32][33];
    const int bid = blockIdx.x;
    if (bid < 8192) {
        int i = bid * 256 + threadIdx.x;
        float4 v = ((const float4*)x)[i];
        ushort4 o;
        o.x = f2bf(v.x); o.y = f2bf(v.y); o.z = f2bf(v.z); o.w = f2bf(v.w);
        ((ushort4*)x_bf)[i] = o;
        return;
    }
    const float* W;
    unsigned short* Wt;
    int tn, tk, N;
    if (bid < 8192 + 3072) {
        W = w_qkv; Wt = wqkvT; N = 3072;
        tn = (bid - 8192) % 96; tk = (bid - 8192) / 96;
    } else {
        W = w_out; Wt = woutT; N = 1024;
        tn = (bid - 11264) % 32; tk = (bid - 11264) / 32;
    }
    const int K = 1024;
    int lx = threadIdx.x & 31, ly = threadIdx.x >> 5;  // 32 x 8
    #pragma unroll
    for (int i = 0; i < 32; i += 8) {
        int k = tk * 32 + ly + i;
        int n = tn * 32 + lx;
        tile[ly + i][lx] = f2bf(W[(size_t)k * N + n]);
    }
    __syncthreads();
    int k2 = tk * 32 + lx;
    #pragma unroll
    for (int i = 0; i < 32; i += 8) {
        int n2 = tn * 32 + ly + i;
        Wt[(size_t)n2 * K + k2] = tile[lx][ly + i];
    }
}

// --------- C[M][N] = A[M][K] * Bt[N][K]^T   (bf16 in) -----------------------
// BK=64 + row&7 XOR LDS swizzle + bijective XCD block swizzle (R20-proven).
// MODE 0: plain fp32 C. MODE 1: fused QKV epilogue (Q*0.125*log2e|K -> qk,
// V -> vt transposed; strides QKP).
template<int MODE>
__global__ __launch_bounds__(256) void k_gemm_bt(const unsigned short* __restrict__ A,
                                                 const unsigned short* __restrict__ Bt,
                                                 void* __restrict__ Cv,
                                                 unsigned short* __restrict__ vtv,
                                                 int M, int N_, int K) {
    constexpr int BM = 128, BN = 128, BK = 64;
    __shared__ unsigned short lA[BM * BK];
    __shared__ unsigned short lB[BN * BK];
    const int ntile = N_ / BN;
    const int wgid = (blockIdx.x & 7) * (gridDim.x >> 3) + (blockIdx.x >> 3);
    const int tm = wgid / ntile;
    const int tn = wgid % ntile;
    const int t = threadIdx.x;
    const int w = t >> 6, l = t & 63;
    const int wr = w >> 1, wc = w & 1;

    const unsigned short* Abase = A + (size_t)tm * BM * K;
    const unsigned short* Bbase = Bt + (size_t)tn * BN * K;

    f32x4 acc[4][4] = {};
    const int rswz = (l & 7) << 4;

    for (int k0 = 0; k0 < K; k0 += BK) {
        __syncthreads();
        #pragma unroll
        for (int i = 0; i < 4; ++i) {
            const int o  = i * 4096 + t * 16;
            const int so = o ^ (((o >> 7) & 7) << 4);
            gload_lds16((const char*)(Abase + (size_t)(so >> 7) * K + k0) + (so & 127),
                        (char*)lA + i * 4096 + w * 1024);
            gload_lds16((const char*)(Bbase + (size_t)(so >> 7) * K + k0) + (so & 127),
                        (char*)lB + i * 4096 + w * 1024);
        }
        __syncthreads();

        #pragma unroll
        for (int kk = 0; kk < 2; ++kk) {
            bf16x8 af[4], bfv[4];
            #pragma unroll
            for (int i = 0; i < 4; ++i) {
                const int ea = ((wr * 64 + i * 16 + (l & 15)) << 7) + kk * 64 + ((l >> 4) << 4);
                af[i] = *(const bf16x8*)((const char*)lA + (ea ^ rswz));
            }
            #pragma unroll
            for (int j = 0; j < 4; ++j) {
                const int eb = ((wc * 64 + j * 16 + (l & 15)) << 7) + kk * 64 + ((l >> 4) << 4);
                bfv[j] = *(const bf16x8*)((const char*)lB + (eb ^ rswz));
            }
            #pragma unroll
            for (int i = 0; i < 4; ++i)
                #pragma unroll
                for (int j = 0; j < 4; ++j)
                    acc[i][j] = __builtin_amdgcn_mfma_f32_16x16x32_bf16(af[i], bfv[j], acc[i][j], 0, 0, 0);
        }
    }

    const int row0 = tm * BM + wr * 64 + (l >> 4) * 4;
    const int col0 = tn * BN + wc * 64 + (l & 15);

    if (MODE == 0) {
        float* Cf = (float*)Cv;
        #pragma unroll
        for (int i = 0; i < 4; ++i)
            #pragma unroll
            for (int j = 0; j < 4; ++j)
                #pragma unroll
                for (int r = 0; r < 4; ++r)
                    Cf[(size_t)(row0 + i * 16 + r) * N_ + (col0 + j * 16)] = acc[i][j][r];
    } else if (tn < 16) {
        const float cs = (tn < 8) ? 0.125f * LOG2E : 1.0f;
        unsigned short* qk = (unsigned short*)Cv;
        #pragma unroll
        for (int i = 0; i < 4; ++i)
            #pragma unroll
            for (int j = 0; j < 4; ++j)
                #pragma unroll
                for (int r = 0; r < 4; ++r)
                    qk[(size_t)(row0 + i * 16 + r) * QKP + (col0 + j * 16)] = f2bf(acc[i][j][r] * cs);
    } else {
        #pragma unroll
        for (int i = 0; i < 4; ++i) {
            const int rbase = row0 + i * 16;
            const int bq = rbase >> 11;
            const int n0 = rbase & 2047;
            #pragma unroll
            for (int j = 0; j < 4; ++j) {
                const int c = col0 + j * 16 - 2048;
                const int hh = c >> 6, dd = c & 63;
                uint2 u;
                u.x = (unsigned int)f2bf(acc[i][j][0]) | ((unsigned int)f2bf(acc[i][j][1]) << 16);
                u.y = (unsigned int)f2bf(acc[i][j][2]) | ((unsigned int)f2bf(acc[i][j][3]) << 16);
                *(uint2*)(vtv + ((size_t)(bq * 16 + hh) * 64 + dd) * QKP + n0) = u;
            }
        }
    }
}

// -- causal flash attention (v24: LDS-staged, single-chunk blocks x4/CU) -----
// 1024 blocks x 4 waves; block = (bh, chunk c). Per-block work proportional
// to c+1, heavy-first issue; 4 blocks/CU resident hide the per-tile barrier
// drain that capped R23 at 2 blocks/CU. bh = 8*XCD + (j&7) keeps each XCD on
// 8 heads (2MB K/V, L2-local). Body identical to R23.
__global__ __launch_bounds__(256, 2) void k_attn24(const unsigned short* __restrict__ qk,
                                                   const unsigned short* __restrict__ vt,
                                                   unsigned short* __restrict__ out) {
    const int bid = blockIdx.x;               // 1024
    const int xcd = bid & 7;
    const int j = bid >> 3;                   // 0..127
    const int bh = xcd * 8 + (j & 7);         // 8 heads per XCD
    const int c = 15 - (j >> 3);              // heavy chunks first
    const int b = bh >> 4, h = bh & 15;
    const int t = threadIdx.x;
    const int w = t >> 6, l = t & 63;
    const int l31 = l & 31, hi = l >> 5;

    __shared__ unsigned short Kl[2][64 * 64]; // 2 x 8 KB
    __shared__ unsigned short Vl[2][64 * 64]; // 2 x 8 KB

    const unsigned short* qp = qk + (size_t)(b * SEQ) * QKP + h * 64;
    unsigned short* op = out + (size_t)(b * SEQ) * DIMM + h * 64;
    const char* kbase = (const char*)(qk + (size_t)(b * SEQ) * QKP + 1024 + h * 64);
    const char* vbase = (const char*)(vt + (size_t)bh * 64 * QKP);

    const int rswz = (l & 7) << 4;
    union U8 { uint32_t u[4]; bf16x8 v; };

    // stage kv tile (64 rows K + 64 rows V^T, 128B rows) into buffer bs
    auto STAGE = [&](int kv0, int bs) {
        #pragma unroll
        for (int i = 0; i < 2; ++i) {
            const int o  = i * 4096 + t * 16;
            const int so = o ^ (((o >> 7) & 7) << 4);
            const int row = so >> 7, cb = so & 127;
            gload_lds16(kbase + (size_t)(kv0 + row) * (QKP * 2) + cb,
                        (char*)Kl[bs] + i * 4096 + w * 1024);
            gload_lds16(vbase + (size_t)row * (QKP * 2) + kv0 * 2 + cb,
                        (char*)Vl[bs] + i * 4096 + w * 1024);
        }
    };

    const int q0w = c * 128 + w * 32;          // wave's first q row
    const int qrow = q0w + l31;                // this lane's q row
    const int ntw = (q0w >> 6) + 1;            // wave's kv-tile count
    const int ntb = c * 2 + 2;                 // block's kv-tile count

    // Q as B-operand (prescaled 1/8*log2e)
    bf16x8 qf[4];
    #pragma unroll
    for (int m = 0; m < 4; ++m)
        qf[m] = *(const bf16x8*)(qp + (size_t)(q0w + l31) * QKP + m * 16 + hi * 8);

    f32x16 accO0 = {}, accO1 = {};
    float m_run = -INFINITY, l_run = 0.f;

    STAGE(0, 0);
    __syncthreads();   // implicit vmcnt(0) drain -> buf0 ready

    // one kv-tile of compute; MSK is compile-time
    auto tile = [&](int kt, auto mskc) {
        constexpr bool MSK = decltype(mskc)::value;
        const int kv0 = kt * 64;
        const char* kl = (const char*)Kl[kt & 1];
        const char* vl = (const char*)Vl[kt & 1];

        // K fragments from LDS (row f*32+l31, col m*16+hi*8)
        bf16x8 kf[2][4];
        #pragma unroll
        for (int f = 0; f < 2; ++f)
            #pragma unroll
            for (int m = 0; m < 4; ++m) {
                const int ea = ((f * 32 + l31) << 7) + m * 32 + hi * 16;
                kf[f][m] = *(const bf16x8*)(kl + (ea ^ rswz));
            }

        // QK^T swapped -> S^T
        f32x16 s0 = {}, s1 = {};
        __builtin_amdgcn_s_setprio(1);
        #pragma unroll
        for (int m = 0; m < 4; ++m) {
            s0 = __builtin_amdgcn_mfma_f32_32x32x16_bf16(kf[0][m], qf[m], s0, 0, 0, 0);
            s1 = __builtin_amdgcn_mfma_f32_32x32x16_bf16(kf[1][m], qf[m], s1, 0, 0, 0);
        }
        __builtin_amdgcn_s_setprio(0);

        // V^T fragments from LDS (row = d, col = kv)
        bf16x8 vf0[4], vf1[4];
        #pragma unroll
        for (int m = 0; m < 4; ++m) {
            const int e0 = (l31 << 7) + m * 32 + hi * 16;
            const int e1 = ((32 + l31) << 7) + m * 32 + hi * 16;
            vf0[m] = *(const bf16x8*)(vl + (e0 ^ rswz));
            vf1[m] = *(const bf16x8*)(vl + (e1 ^ rswz));
        }

        // ---- in-lane online softmax, exp2 domain, defer-max ----
        float tmax = -1e30f;
        #pragma unroll
        for (int r = 0; r < 16; ++r) {
            float v0 = s0[r];
            float v1 = s1[r];
            if (MSK) {
                const int crow = (r & 3) + 8 * (r >> 2) + 4 * hi;
                if (kv0 + crow > qrow)      v0 = -1e30f;
                if (kv0 + 32 + crow > qrow) v1 = -1e30f;
                s0[r] = v0; s1[r] = v1;
            }
            tmax = fmaxf(tmax, fmaxf(v0, v1));
        }
        tmax = fmaxf(tmax, __shfl_xor(tmax, 32));
        const bool defer = __all(tmax <= m_run + 8.0f);
        float fct = 1.0f;
        if (!defer) {
            const float mnew = fmaxf(m_run, tmax);
            fct = exp2f(m_run - mnew);
            m_run = mnew;
            #pragma unroll
            for (int r = 0; r < 16; ++r) { accO0[r] *= fct; accO1[r] *= fct; }
        }
        float ps = 0.f;
        #pragma unroll
        for (int r = 0; r < 16; ++r) {
            float p0 = exp2f(s0[r] - m_run);
            float p1 = exp2f(s1[r] - m_run);
            s0[r] = p0; s1[r] = p1;
            ps += p0 + p1;
        }
        ps += __shfl_xor(ps, 32);
        l_run = l_run * fct + ps;

        // ---- P -> bf16 pack + permlane + PV (O^T) ----
        uint32_t pw0[8], pw1[8];
        #pragma unroll
        for (int i = 0; i < 8; ++i) {
            asm("v_cvt_pk_bf16_f32 %0, %1, %2" : "=v"(pw0[i]) : "v"(s0[2*i]), "v"(s0[2*i+1]));
            asm("v_cvt_pk_bf16_f32 %0, %1, %2" : "=v"(pw1[i]) : "v"(s1[2*i]), "v"(s1[2*i+1]));
        }
        __builtin_amdgcn_s_setprio(1);
        #define PVCHUNK(PW, BASE, VF0, VF1) do {                                     \
            uint32_t a0 = PW[BASE+0], b0 = PW[BASE+2];                               \
            uint32_t a1 = PW[BASE+1], b1 = PW[BASE+3];                               \
            asm("v_permlane32_swap_b32 %0, %1" : "+v"(a0), "+v"(b0));                \
            asm("v_permlane32_swap_b32 %0, %1" : "+v"(a1), "+v"(b1));                \
            U8 pb; pb.u[0] = a0; pb.u[1] = a1; pb.u[2] = b0; pb.u[3] = b1;           \
            accO0 = __builtin_amdgcn_mfma_f32_32x32x16_bf16(VF0, pb.v, accO0, 0, 0, 0); \
            accO1 = __builtin_amdgcn_mfma_f32_32x32x16_bf16(VF1, pb.v, accO1, 0, 0, 0); \
        } while (0)
        PVCHUNK(pw0, 0, vf0[0], vf1[0]);
        PVCHUNK(pw0, 4, vf0[1], vf1[1]);
        PVCHUNK(pw1, 0, vf0[2], vf1[2]);
        PVCHUNK(pw1, 4, vf0[3], vf1[3]);
        #undef PVCHUNK
        __builtin_amdgcn_s_setprio(0);
    };

    for (int kt = 0; kt < ntb; ++kt) {
        if (kt + 1 < ntb) STAGE((kt + 1) * 64, (kt + 1) & 1);

        if (kt < ntw - 1)       tile(kt, BoolC<false>{});
        else if (kt == ntw - 1) tile(kt, BoolC<true>{});

        __syncthreads();   // all reads of buf[kt&1] done; STAGE(kt+1) drained
    }

    // epilogue: lane holds O[q = q0w+l31][d = crow + {0,32}], own l_run
    const float inv = 1.0f / l_run;
    unsigned short* orow = op + (size_t)(q0w + l31) * DIMM;
    #pragma unroll
    for (int g = 0; g < 4; ++g) {
        uint2 u0, u1;
        float a0 = accO0[4*g+0] * inv, a1 = accO0[4*g+1] * inv;
        float a2 = accO0[4*g+2] * inv, a3 = accO0[4*g+3] * inv;
        float c0 = accO1[4*g+0] * inv, c1 = accO1[4*g+1] * inv;
        float c2 = accO1[4*g+2] * inv, c3 = accO1[4*g+3] * inv;
        asm("v_cvt_pk_bf16_f32 %0, %1, %2" : "=v"(u0.x) : "v"(a0), "v"(a1));
        asm("v_cvt_pk_bf16_f32 %0, %1, %2" : "=v"(u0.y) : "v"(a2), "v"(a3));
        asm("v_cvt_pk_bf16_f32 %0, %1, %2" : "=v"(u1.x) : "v"(c0), "v"(c1));
        asm("v_cvt_pk_bf16_f32 %0, %1, %2" : "=v"(u1.y) : "v"(c2), "v"(c3));
        *(uint2*)(orow + 8*g + 4*hi)      = u0;   // d = 8g+4hi .. +3
        *(uint2*)(orow + 32 + 8*g + 4*hi) = u1;   // d = 32+8g+4hi .. +3
    }
}

// ---------------------------------------------------------------------------
extern "C" void kernel_launch(void* const* d_in, const int* in_sizes, int n_in,
                              void* d_out, int out_size, void* d_ws, size_t ws_size,
                              hipStream_t stream) {
    const float* x     = (const float*)d_in[0];   // [4,2048,1024]
    const float* w_qkv = (const float*)d_in[1];   // [1024,3072]
    const float* w_out = (const float*)d_in[2];   // [1024,1024]

    unsigned short* x_bf   = (unsigned short*)d_ws;
    unsigned short* wqkvT  = x_bf   + (size_t)MROWS * DIMM;
    unsigned short* woutT  = wqkvT  + (size_t)3 * DIMM * DIMM;
    unsigned short* qk_buf = woutT  + (size_t)DIMM * DIMM;           // [8192][QKP]
    unsigned short* vt     = qk_buf + (size_t)MROWS * QKP;           // [64][64][QKP]
    unsigned short* aout   = vt     + (size_t)64 * DH * QKP;         // [8192][1024]

    // 1. fused prep: conv + both weight transposes in one dispatch
    k_prep<<<8192 + 3072 + 1024, 256, 0, stream>>>(x, x_bf, w_qkv, wqkvT, w_out, woutT);

    // 2. QKV projection (R20-proven): Q(scaled)|K -> qk_buf, V^T -> vt
    k_gemm_bt<1><<<(MROWS / 128) * (3 * DIMM / 128), 256, 0, stream>>>(
        x_bf, wqkvT, qk_buf, vt, MROWS, 3 * DIMM, DIMM);

    // 3. causal flash attention (single-chunk blocks, 4 blocks/CU)
    k_attn24<<<1024, 256, 0, stream>>>(qk_buf, vt, aout);

    // 4. output projection: [8192,1024] x [1024,1024] -> fp32 d_out
    k_gemm_bt<0><<<(MROWS / 128) * (DIMM / 128), 256, 0, stream>>>(
        aout, woutT, d_out, nullptr, MROWS, DIMM, DIMM);
}